// Round 3
// baseline (293.965 us; speedup 1.0000x reference)
//
#include <hip/hip_runtime.h>
#include <math.h>

#define BB 16
#define NN 2048
#define DD 1024
#define KH 15
#define KL 5
#define NH 240      // BB*KH
#define NBANK 320   // BB*(KH+KL)
#define NCH 16      // n-chunks (16 chunks x 20 rows)
#define NGRAM (80 * NCH)   // 1280 gram blocks

// ws layout (4-byte words):
#define WS_BAGMAX 0      // float[16]
#define WS_BAGSUM 32     // float[16]
#define WS_DONE   48     // int: gram-block done counter
#define WS_SELH   64     // int[240]
#define WS_SELL   320    // int[80]
#define WS_PNUM   512    // float[5120]: pnum[q*16+chunk]
#define WS_PDEN   5632   // float[5120]

// ---------------- fused stats + select: 16 blocks x 256 ----------------
// Global gmax/gmin computed redundantly per block (2 MB total L2 reads, free).
// Selection on wave 0 with all 2048 keys in VGPRs (32 x u64/lane) -> zero
// __syncthreads in the extraction rounds.
__global__ void __launch_bounds__(256) k_selstat(const float* __restrict__ score,
                                                 float* __restrict__ ws,
                                                 int* __restrict__ selH,
                                                 int* __restrict__ selL) {
    int b = blockIdx.x, t = threadIdx.x;
    if (b == 0 && t == 0) ((int*)ws)[WS_DONE] = 0;   // ws poisoned each call;
                                                     // visible to k_gram via stream order
    __shared__ float s_score[NN];                    // own bag staged for wave 0
    __shared__ float rgx[256], rgn[256], rbx[256], rbs[256];

    const float4* s4 = (const float4*)score;         // 8192 float4 total
    float gmx = -1e30f, gmn = 1e30f;
    for (int j = t; j < (BB * NN) / 4; j += 256) {   // 32 f4/thread, coalesced
        float4 v = s4[j];
        gmx = fmaxf(gmx, fmaxf(fmaxf(v.x, v.y), fmaxf(v.z, v.w)));
        gmn = fminf(gmn, fminf(fminf(v.x, v.y), fminf(v.z, v.w)));
    }
    float bmx = -1e30f, bsm = 0.f;
    for (int j = t; j < NN / 4; j += 256) {          // own bag: 2 f4/thread
        float4 v = s4[b * (NN / 4) + j];
        bmx = fmaxf(bmx, fmaxf(fmaxf(v.x, v.y), fmaxf(v.z, v.w)));
        bsm += v.x + v.y + v.z + v.w;
        ((float4*)s_score)[j] = v;
    }
    rgx[t] = gmx; rgn[t] = gmn; rbx[t] = bmx; rbs[t] = bsm;
    __syncthreads();
    for (int s2 = 128; s2 > 0; s2 >>= 1) {
        if (t < s2) {
            rgx[t] = fmaxf(rgx[t], rgx[t + s2]);
            rgn[t] = fminf(rgn[t], rgn[t + s2]);
            rbx[t] = fmaxf(rbx[t], rbx[t + s2]);
            rbs[t] += rbs[t + s2];
        }
        __syncthreads();
    }
    if (t == 0) {
        ws[WS_BAGMAX + b] = rbx[0];                  // finalize: Dm = mean/max
        ws[WS_BAGSUM + b] = rbs[0];
    }
    if (t >= 64) return;                             // extraction: wave 0 only
    float sgmax = rgx[0], sgmin = rgn[0];            // valid: loop ended w/ barrier

    const unsigned long long INV = ~0ULL;
    int l = t;
    // key = (score_bits<<32)|idx reproduces jnp stable argsort (scores >= 0).
    unsigned long long key[32];
    #pragma unroll
    for (int j = 0; j < 32; ++j) {
        int idx = l + 64 * j;                        // conflict-free LDS reads
        key[j] = ((unsigned long long)__float_as_uint(s_score[idx]) << 32)
               | (unsigned)idx;
    }

    // ---- H band: 15 smallest with score >= gmax-0.3 ----
    float hlo = sgmax - 0.3f;
    unsigned int mask = 0u;
    #pragma unroll
    for (int j = 0; j < 32; ++j)
        if (__uint_as_float((unsigned)(key[j] >> 32)) >= hlo) mask |= (1u << j);
    int r = 0;
    for (; r < KH; ++r) {
        unsigned long long v = INV;
        #pragma unroll
        for (int j = 0; j < 32; ++j)
            if ((mask & (1u << j)) && key[j] < v) v = key[j];
        #pragma unroll
        for (int s2 = 32; s2 > 0; s2 >>= 1) {
            unsigned long long o = __shfl_xor(v, s2);
            if (o < v) v = o;
        }
        if (v == INV) break;                         // uniform after butterfly
        if (l == 0) selH[b * KH + r] = (int)(v & 0xffffffffu);
        #pragma unroll
        for (int j = 0; j < 32; ++j)
            if (key[j] == v) mask &= ~(1u << j);     // keys unique (idx embedded)
    }
    if (l == 0) for (int k = r; k < KH; ++k) selH[b * KH + k] = -1;

    // ---- L band: even ranks among [gmin, gmin+1e-9] ----
    float llo = sgmin, lhi = sgmin + 1e-9f;
    mask = 0u;
    #pragma unroll
    for (int j = 0; j < 32; ++j) {
        float s = __uint_as_float((unsigned)(key[j] >> 32));
        if (s >= llo && s <= lhi) mask |= (1u << j);
    }
    int nsel = 0;
    for (int rr = 0; rr < 2 * KL; ++rr) {
        unsigned long long v = INV;
        #pragma unroll
        for (int j = 0; j < 32; ++j)
            if ((mask & (1u << j)) && key[j] < v) v = key[j];
        #pragma unroll
        for (int s2 = 32; s2 > 0; s2 >>= 1) {
            unsigned long long o = __shfl_xor(v, s2);
            if (o < v) v = o;
        }
        if (v == INV) break;
        if ((rr & 1) == 0) {
            if (l == 0) selL[b * KL + (rr >> 1)] = (int)(v & 0xffffffffu);
            nsel++;
        }
        #pragma unroll
        for (int j = 0; j < 32; ++j)
            if (key[j] == v) mask &= ~(1u << j);
    }
    if (l == 0) for (int k = nsel; k < KL; ++k) selL[b * KL + k] = -1;
}

// ---- Gram partials + fused finalize: 1280 blocks (80 q-quads x 16 n-chunks) ----
// 16-way n-split: each wave owns only 5 serial dot products (was 20) and the
// grid fills 5 waves/SIMD (was 1.25) -> latency-bound critical path / 4.
__global__ void __launch_bounds__(256) k_gram(const float* __restrict__ fea,
                                              const int* __restrict__ selH,
                                              const int* __restrict__ selL,
                                              const int* __restrict__ label,
                                              const float* __restrict__ t_logit,
                                              const float* __restrict__ ori,
                                              const float* __restrict__ l2w,
                                              float* __restrict__ ws,
                                              float* __restrict__ out) {
    const int blk = blockIdx.x, t = threadIdx.x;
    const int g = blk >> 4;          // q-quad 0..79
    const int h = blk & 15;          // n-chunk 0..15 (20 rows each)
    const int q0 = g * 4;
    __shared__ int s_row[20], s_lab[20];
    __shared__ int s_qrow[4], s_qt[4];
    if (t < 20) {
        int n = h * 20 + t;          // global bank index
        int bn, in_, ln;
        if (n < NH) { bn = n / KH; in_ = selH[n]; ln = label[bn]; }
        else        { bn = (n - NH) / KL; in_ = selL[n - NH]; ln = 2; }
        s_row[t] = (in_ >= 0) ? bn * NN + in_ : -1;
        s_lab[t] = ln;
    }
    if (t >= 32 && t < 36) {
        int q = q0 + (t - 32); int bq, iq, qt;
        if (q < NH) { bq = q / KH; iq = selH[q]; qt = label[bq]; }
        else        { bq = (q - NH) / KL; iq = selL[q - NH]; qt = 2; }
        s_qrow[t - 32] = (iq >= 0) ? bq * NN + iq : 0;  // fallback; masked in finalize
        s_qt[t - 32] = qt;
    }
    __syncthreads();
    const int w = t >> 6, l = t & 63;
    const float4* qp0 = (const float4*)(fea + (size_t)s_qrow[0] * DD);
    const float4* qp1 = (const float4*)(fea + (size_t)s_qrow[1] * DD);
    const float4* qp2 = (const float4*)(fea + (size_t)s_qrow[2] * DD);
    const float4* qp3 = (const float4*)(fea + (size_t)s_qrow[3] * DD);
    const int qt0 = s_qt[0], qt1 = s_qt[1], qt2 = s_qt[2], qt3 = s_qt[3];
    // q fragments hoisted to registers: 16 float4 = 64 VGPR, loaded once
    float4 q0v[4], q1v[4], q2v[4], q3v[4];
    #pragma unroll
    for (int c = 0; c < 4; ++c) {
        q0v[c] = qp0[c * 64 + l];
        q1v[c] = qp1[c * 64 + l];
        q2v[c] = qp2[c * 64 + l];
        q3v[c] = qp3[c * 64 + l];
    }
    float d0 = 0, d1 = 0, d2 = 0, d3 = 0;
    float n0 = 0, n1 = 0, n2 = 0, n3 = 0;
    #pragma unroll
    for (int k = 0; k < 5; ++k) {                // wave w: local n in [w*5, w*5+5)
        int rn = s_row[w * 5 + k];
        if (rn < 0) continue;                    // wave-uniform branch
        const float4* np_ = (const float4*)(fea + (size_t)rn * DD);
        float a0 = 0, a1 = 0, a2 = 0, a3 = 0;
        #pragma unroll
        for (int c = 0; c < 4; ++c) {
            float4 nv = np_[c * 64 + l];         // coalesced: 64 lanes x 16B contiguous
            a0 += nv.x * q0v[c].x + nv.y * q0v[c].y + nv.z * q0v[c].z + nv.w * q0v[c].w;
            a1 += nv.x * q1v[c].x + nv.y * q1v[c].y + nv.z * q1v[c].z + nv.w * q1v[c].w;
            a2 += nv.x * q2v[c].x + nv.y * q2v[c].y + nv.z * q2v[c].z + nv.w * q2v[c].w;
            a3 += nv.x * q3v[c].x + nv.y * q3v[c].y + nv.z * q3v[c].z + nv.w * q3v[c].w;
        }
        #pragma unroll
        for (int s2 = 32; s2 > 0; s2 >>= 1) {    // butterfly: all lanes get full dot
            a0 += __shfl_xor(a0, s2);
            a1 += __shfl_xor(a1, s2);
            a2 += __shfl_xor(a2, s2);
            a3 += __shfl_xor(a3, s2);
        }
        int ln = s_lab[w * 5 + k];
        float e;
        e = __expf(a0 * 0.0625f); d0 += e; if (ln == qt0) n0 += e;
        e = __expf(a1 * 0.0625f); d1 += e; if (ln == qt1) n1 += e;
        e = __expf(a2 * 0.0625f); d2 += e; if (ln == qt2) n2 += e;
        e = __expf(a3 * 0.0625f); d3 += e; if (ln == qt3) n3 += e;
    }
    __shared__ float s_pn[4][4], s_pd[4][4];     // [wave][q]
    if (l == 0) {
        s_pn[w][0] = n0; s_pn[w][1] = n1; s_pn[w][2] = n2; s_pn[w][3] = n3;
        s_pd[w][0] = d0; s_pd[w][1] = d1; s_pd[w][2] = d2; s_pd[w][3] = d3;
    }
    __syncthreads();
    if (t < 4) {
        float num = 0, den = 0;
        for (int ww = 0; ww < 4; ++ww) { num += s_pn[ww][t]; den += s_pd[ww][t]; }
        ws[WS_PNUM + (q0 + t) * NCH + h] = num;
        ws[WS_PDEN + (q0 + t) * NCH + h] = den;
    }

    // ---- last-block-done fused finalize ----
    __shared__ int s_old;
    __threadfence();                              // release partial writes (device scope)
    if (t == 0) s_old = atomicAdd((int*)ws + WS_DONE, 1);
    __syncthreads();
    if (s_old != NGRAM - 1) return;
    __threadfence();                              // acquire: see all blocks' partials

    __shared__ float sper[NBANK], sval[NBANK];
    __shared__ float sc16[16], sce[16];
    for (int q = t; q < NBANK; q += 256) {
        float num = 0, den = 0;
        #pragma unroll
        for (int hh = 0; hh < NCH; ++hh) {
            num += ws[WS_PNUM + q * NCH + hh];
            den += ws[WS_PDEN + q * NCH + hh];
        }
        bool valid = (q < NH) ? (selH[q] >= 0) : (selL[q - NH] >= 0);
        sper[q] = valid ? (logf(den) - logf(num)) : 0.f;
        sval[q] = valid ? 1.f : 0.f;
    }
    __syncthreads();
    if (t < 16) {
        float s = 0, c = 0;
        for (int k = 0; k < KH; ++k) { s += sper[t * KH + k]; c += sval[t * KH + k]; }
        for (int k = 0; k < KL; ++k) { int q = NH + t * KL + k; s += sper[q]; c += sval[q]; }
        sc16[t] = s / c;
    } else if (t >= 64 && t < 80) {
        int b2 = t - 64;
        sce[b2] = logf(expf(ori[2 * b2]) + expf(ori[2 * b2 + 1])) - t_logit[0];
    }
    __syncthreads();
    if (t == 0) {
        float contrast = 0, ce = 0;
        for (int b2 = 0; b2 < 16; ++b2) { contrast += sc16[b2]; ce += sce[b2]; }
        contrast *= (1.f / 16.f); ce *= (1.f / 16.f);
        float gmax = -1e30f, ssum = 0.f;
        for (int i = 0; i < 16; ++i) {
            gmax = fmaxf(gmax, ws[WS_BAGMAX + i]);
            ssum += ws[WS_BAGSUM + i];
        }
        float Dm = (ssum / (float)(BB * NN)) / gmax;
        float l2 = 1e-4f * (1.f - Dm) * (1.f - Dm) * l2w[0];
        out[0] = contrast + ce + l2;
    }
}

extern "C" void kernel_launch(void* const* d_in, const int* in_sizes, int n_in,
                              void* d_out, int out_size, void* d_ws, size_t ws_size,
                              hipStream_t stream) {
    const float* fea     = (const float*)d_in[0];
    const float* score   = (const float*)d_in[1];
    const int*   label   = (const int*)d_in[2];
    const float* t_logit = (const float*)d_in[3];
    const float* ori     = (const float*)d_in[4];
    const float* l2_wei  = (const float*)d_in[5];
    float* ws  = (float*)d_ws;
    int* selH  = (int*)d_ws + WS_SELH;
    int* selL  = (int*)d_ws + WS_SELL;
    float* out = (float*)d_out;

    hipLaunchKernelGGL(k_selstat, dim3(BB),    dim3(256), 0, stream, score, ws, selH, selL);
    hipLaunchKernelGGL(k_gram,    dim3(NGRAM), dim3(256), 0, stream, fea, selH, selL, label,
                       t_logit, ori, l2_wei, ws, out);
}

// Round 4
// 220.596 us; speedup vs baseline: 1.3326x; 1.3326x over previous
//
#include <hip/hip_runtime.h>
#include <math.h>

#define BB 16
#define NN 2048
#define DD 1024
#define KH 15
#define KL 5
#define NH 240      // BB*KH
#define NBANK 320   // BB*(KH+KL)

// ws layout (4-byte words):
#define WS_BAGMAX 0      // float[16]
#define WS_BAGSUM 32     // float[16]
#define WS_SELH   64     // int[240]
#define WS_SELL   320    // int[80]
#define WS_PNUM   512    // float[1280]: pnum[q*4+quarter]
#define WS_PDEN   1792   // float[1280]

// ---------------- fused stats + select: 16 blocks x 256 ----------------
// Global gmax/gmin computed redundantly per block (2 MB total L2 reads, free).
// Selection on wave 0 with all 2048 keys in VGPRs (32 x u64/lane) -> zero
// __syncthreads in the extraction rounds.
__global__ void __launch_bounds__(256) k_selstat(const float* __restrict__ score,
                                                 float* __restrict__ ws,
                                                 int* __restrict__ selH,
                                                 int* __restrict__ selL) {
    int b = blockIdx.x, t = threadIdx.x;
    __shared__ float s_score[NN];                    // own bag staged for wave 0
    __shared__ float rgx[256], rgn[256], rbx[256], rbs[256];

    const float4* s4 = (const float4*)score;         // 8192 float4 total
    float gmx = -1e30f, gmn = 1e30f;
    for (int j = t; j < (BB * NN) / 4; j += 256) {   // 32 f4/thread, coalesced
        float4 v = s4[j];
        gmx = fmaxf(gmx, fmaxf(fmaxf(v.x, v.y), fmaxf(v.z, v.w)));
        gmn = fminf(gmn, fminf(fminf(v.x, v.y), fminf(v.z, v.w)));
    }
    float bmx = -1e30f, bsm = 0.f;
    for (int j = t; j < NN / 4; j += 256) {          // own bag: 2 f4/thread
        float4 v = s4[b * (NN / 4) + j];
        bmx = fmaxf(bmx, fmaxf(fmaxf(v.x, v.y), fmaxf(v.z, v.w)));
        bsm += v.x + v.y + v.z + v.w;
        ((float4*)s_score)[j] = v;
    }
    rgx[t] = gmx; rgn[t] = gmn; rbx[t] = bmx; rbs[t] = bsm;
    __syncthreads();
    for (int s2 = 128; s2 > 0; s2 >>= 1) {
        if (t < s2) {
            rgx[t] = fmaxf(rgx[t], rgx[t + s2]);
            rgn[t] = fminf(rgn[t], rgn[t + s2]);
            rbx[t] = fmaxf(rbx[t], rbx[t + s2]);
            rbs[t] += rbs[t + s2];
        }
        __syncthreads();
    }
    if (t == 0) {
        ws[WS_BAGMAX + b] = rbx[0];                  // finalize: Dm = mean/max
        ws[WS_BAGSUM + b] = rbs[0];
    }
    if (t >= 64) return;                             // extraction: wave 0 only
    float sgmax = rgx[0], sgmin = rgn[0];            // valid: loop ended w/ barrier

    const unsigned long long INV = ~0ULL;
    int l = t;
    // key = (score_bits<<32)|idx reproduces jnp stable argsort (scores >= 0).
    unsigned long long key[32];
    #pragma unroll
    for (int j = 0; j < 32; ++j) {
        int idx = l + 64 * j;                        // conflict-free LDS reads
        key[j] = ((unsigned long long)__float_as_uint(s_score[idx]) << 32)
               | (unsigned)idx;
    }

    // ---- H band: 15 smallest with score >= gmax-0.3 ----
    float hlo = sgmax - 0.3f;
    unsigned int mask = 0u;
    #pragma unroll
    for (int j = 0; j < 32; ++j)
        if (__uint_as_float((unsigned)(key[j] >> 32)) >= hlo) mask |= (1u << j);
    int r = 0;
    for (; r < KH; ++r) {
        unsigned long long v = INV;
        #pragma unroll
        for (int j = 0; j < 32; ++j)
            if ((mask & (1u << j)) && key[j] < v) v = key[j];
        #pragma unroll
        for (int s2 = 32; s2 > 0; s2 >>= 1) {
            unsigned long long o = __shfl_xor(v, s2);
            if (o < v) v = o;
        }
        if (v == INV) break;                         // uniform after butterfly
        if (l == 0) selH[b * KH + r] = (int)(v & 0xffffffffu);
        #pragma unroll
        for (int j = 0; j < 32; ++j)
            if (key[j] == v) mask &= ~(1u << j);     // keys unique (idx embedded)
    }
    if (l == 0) for (int k = r; k < KH; ++k) selH[b * KH + k] = -1;

    // ---- L band: even ranks among [gmin, gmin+1e-9] ----
    float llo = sgmin, lhi = sgmin + 1e-9f;
    mask = 0u;
    #pragma unroll
    for (int j = 0; j < 32; ++j) {
        float s = __uint_as_float((unsigned)(key[j] >> 32));
        if (s >= llo && s <= lhi) mask |= (1u << j);
    }
    int nsel = 0;
    for (int rr = 0; rr < 2 * KL; ++rr) {
        unsigned long long v = INV;
        #pragma unroll
        for (int j = 0; j < 32; ++j)
            if ((mask & (1u << j)) && key[j] < v) v = key[j];
        #pragma unroll
        for (int s2 = 32; s2 > 0; s2 >>= 1) {
            unsigned long long o = __shfl_xor(v, s2);
            if (o < v) v = o;
        }
        if (v == INV) break;
        if ((rr & 1) == 0) {
            if (l == 0) selL[b * KL + (rr >> 1)] = (int)(v & 0xffffffffu);
            nsel++;
        }
        #pragma unroll
        for (int j = 0; j < 32; ++j)
            if (key[j] == v) mask &= ~(1u << j);
    }
    if (l == 0) for (int k = nsel; k < KL; ++k) selL[b * KL + k] = -1;
}

// ---- Gram partials: 320 blocks (80 q-quads x 4 n-quarters) ----
// NO inter-block handshake: blocks write 8 partial words and exit.
// (Round-3 lesson: per-block __threadfence + atomicAdd on one cache line
//  serialized the whole grid — 1280 blocks -> 99 us of pure stall.)
__global__ void __launch_bounds__(256) k_gram(const float* __restrict__ fea,
                                              const int* __restrict__ selH,
                                              const int* __restrict__ selL,
                                              const int* __restrict__ label,
                                              float* __restrict__ ws) {
    const int blk = blockIdx.x, t = threadIdx.x;
    const int g = blk >> 2, h = blk & 3;
    const int q0 = g * 4;
    __shared__ int s_row[80], s_lab[80];
    __shared__ int s_qrow[4], s_qt[4];
    // stage the 80 bank rows for this quarter (waves 0-1) and the 4 q-rows
    // (wave 2) concurrently
    if (t < 80) {
        int n = h * 80 + t;
        int bn, in_, ln;
        if (n < NH) { bn = n / KH; in_ = selH[n]; ln = label[bn]; }
        else        { bn = (n - NH) / KL; in_ = selL[n - NH]; ln = 2; }
        s_row[t] = (in_ >= 0) ? bn * NN + in_ : -1;
        s_lab[t] = ln;
    }
    if (t >= 128 && t < 132) {
        int q = q0 + (t - 128); int bq, iq, qt;
        if (q < NH) { bq = q / KH; iq = selH[q]; qt = label[bq]; }
        else        { bq = (q - NH) / KL; iq = selL[q - NH]; qt = 2; }
        s_qrow[t - 128] = (iq >= 0) ? bq * NN + iq : 0;  // fallback; masked in finalize
        s_qt[t - 128] = qt;
    }
    __syncthreads();
    const int w = t >> 6, l = t & 63;
    const float4* qp0 = (const float4*)(fea + (size_t)s_qrow[0] * DD);
    const float4* qp1 = (const float4*)(fea + (size_t)s_qrow[1] * DD);
    const float4* qp2 = (const float4*)(fea + (size_t)s_qrow[2] * DD);
    const float4* qp3 = (const float4*)(fea + (size_t)s_qrow[3] * DD);
    const int qt0 = s_qt[0], qt1 = s_qt[1], qt2 = s_qt[2], qt3 = s_qt[3];
    // q fragments hoisted to registers: 16 float4 = 64 VGPR, loaded once
    float4 q0v[4], q1v[4], q2v[4], q3v[4];
    #pragma unroll
    for (int c = 0; c < 4; ++c) {
        q0v[c] = qp0[c * 64 + l];
        q1v[c] = qp1[c * 64 + l];
        q2v[c] = qp2[c * 64 + l];
        q3v[c] = qp3[c * 64 + l];
    }
    float d0 = 0, d1 = 0, d2 = 0, d3 = 0;
    float n0 = 0, n1 = 0, n2 = 0, n3 = 0;
    for (int k = 0; k < 20; ++k) {               // wave w: local n in [w*20, w*20+20)
        int rn = s_row[w * 20 + k];
        if (rn < 0) continue;                    // wave-uniform branch
        const float4* np_ = (const float4*)(fea + (size_t)rn * DD);
        float a0 = 0, a1 = 0, a2 = 0, a3 = 0;
        #pragma unroll
        for (int c = 0; c < 4; ++c) {
            float4 nv = np_[c * 64 + l];         // coalesced: 64 lanes x 16B contiguous
            a0 += nv.x * q0v[c].x + nv.y * q0v[c].y + nv.z * q0v[c].z + nv.w * q0v[c].w;
            a1 += nv.x * q1v[c].x + nv.y * q1v[c].y + nv.z * q1v[c].z + nv.w * q1v[c].w;
            a2 += nv.x * q2v[c].x + nv.y * q2v[c].y + nv.z * q2v[c].z + nv.w * q2v[c].w;
            a3 += nv.x * q3v[c].x + nv.y * q3v[c].y + nv.z * q3v[c].z + nv.w * q3v[c].w;
        }
        #pragma unroll
        for (int s2 = 32; s2 > 0; s2 >>= 1) {    // butterfly: all lanes get full dot
            a0 += __shfl_xor(a0, s2);
            a1 += __shfl_xor(a1, s2);
            a2 += __shfl_xor(a2, s2);
            a3 += __shfl_xor(a3, s2);
        }
        int ln = s_lab[w * 20 + k];
        float e;
        e = __expf(a0 * 0.0625f); d0 += e; if (ln == qt0) n0 += e;
        e = __expf(a1 * 0.0625f); d1 += e; if (ln == qt1) n1 += e;
        e = __expf(a2 * 0.0625f); d2 += e; if (ln == qt2) n2 += e;
        e = __expf(a3 * 0.0625f); d3 += e; if (ln == qt3) n3 += e;
    }
    __shared__ float s_pn[4][4], s_pd[4][4];     // [wave][q]
    if (l == 0) {
        s_pn[w][0] = n0; s_pn[w][1] = n1; s_pn[w][2] = n2; s_pn[w][3] = n3;
        s_pd[w][0] = d0; s_pd[w][1] = d1; s_pd[w][2] = d2; s_pd[w][3] = d3;
    }
    __syncthreads();
    if (t < 4) {
        float num = 0, den = 0;
        for (int ww = 0; ww < 4; ++ww) { num += s_pn[ww][t]; den += s_pd[ww][t]; }
        ws[WS_PNUM + (q0 + t) * 4 + h] = num;
        ws[WS_PDEN + (q0 + t) * 4 + h] = den;
    }
    // exit — visibility to k_final is guaranteed by stream ordering
}

// ---- finalize: 1 block x 256 ----
__global__ void __launch_bounds__(256) k_final(const int* __restrict__ selH,
                                               const int* __restrict__ selL,
                                               const float* __restrict__ t_logit,
                                               const float* __restrict__ ori,
                                               const float* __restrict__ l2w,
                                               const float* __restrict__ ws,
                                               float* __restrict__ out) {
    const int t = threadIdx.x;
    __shared__ float sper[NBANK], sval[NBANK];
    __shared__ float sc16[16], sce[16];
    for (int q = t; q < NBANK; q += 256) {
        float num = 0, den = 0;
        #pragma unroll
        for (int hh = 0; hh < 4; ++hh) {
            num += ws[WS_PNUM + q * 4 + hh];
            den += ws[WS_PDEN + q * 4 + hh];
        }
        bool valid = (q < NH) ? (selH[q] >= 0) : (selL[q - NH] >= 0);
        sper[q] = valid ? (logf(den) - logf(num)) : 0.f;
        sval[q] = valid ? 1.f : 0.f;
    }
    __syncthreads();
    if (t < 16) {
        float s = 0, c = 0;
        for (int k = 0; k < KH; ++k) { s += sper[t * KH + k]; c += sval[t * KH + k]; }
        for (int k = 0; k < KL; ++k) { int q = NH + t * KL + k; s += sper[q]; c += sval[q]; }
        sc16[t] = s / c;
    } else if (t >= 64 && t < 80) {
        int b2 = t - 64;
        sce[b2] = logf(expf(ori[2 * b2]) + expf(ori[2 * b2 + 1])) - t_logit[0];
    }
    __syncthreads();
    if (t == 0) {
        float contrast = 0, ce = 0;
        for (int b2 = 0; b2 < 16; ++b2) { contrast += sc16[b2]; ce += sce[b2]; }
        contrast *= (1.f / 16.f); ce *= (1.f / 16.f);
        float gmax = -1e30f, ssum = 0.f;
        for (int i = 0; i < 16; ++i) {
            gmax = fmaxf(gmax, ws[WS_BAGMAX + i]);
            ssum += ws[WS_BAGSUM + i];
        }
        float Dm = (ssum / (float)(BB * NN)) / gmax;
        float l2 = 1e-4f * (1.f - Dm) * (1.f - Dm) * l2w[0];
        out[0] = contrast + ce + l2;
    }
}

extern "C" void kernel_launch(void* const* d_in, const int* in_sizes, int n_in,
                              void* d_out, int out_size, void* d_ws, size_t ws_size,
                              hipStream_t stream) {
    const float* fea     = (const float*)d_in[0];
    const float* score   = (const float*)d_in[1];
    const int*   label   = (const int*)d_in[2];
    const float* t_logit = (const float*)d_in[3];
    const float* ori     = (const float*)d_in[4];
    const float* l2_wei  = (const float*)d_in[5];
    float* ws  = (float*)d_ws;
    int* selH  = (int*)d_ws + WS_SELH;
    int* selL  = (int*)d_ws + WS_SELL;
    float* out = (float*)d_out;

    hipLaunchKernelGGL(k_selstat, dim3(BB),  dim3(256), 0, stream, score, ws, selH, selL);
    hipLaunchKernelGGL(k_gram,    dim3(320), dim3(256), 0, stream, fea, selH, selL, label, ws);
    hipLaunchKernelGGL(k_final,   dim3(1),   dim3(256), 0, stream, selH, selL,
                       t_logit, ori, l2_wei, ws, out);
}